// Round 9
// baseline (480.226 us; speedup 1.0000x reference)
//
#include <hip/hip_runtime.h>
#include <hip/hip_bf16.h>

typedef unsigned short u16;
typedef unsigned int u32;
typedef short bf16x8 __attribute__((ext_vector_type(8)));
typedef float f32x4 __attribute__((ext_vector_type(4)));

__device__ inline float bf2f(u16 u) { return __uint_as_float(((u32)u) << 16); }
__device__ inline u16 f2bf(float f) {
    u32 x = __float_as_uint(f);
    return (u16)((x + 0x7FFFu + ((x >> 16) & 1u)) >> 16);  // RNE
}

// ---------------- Kernel 1: Wh_t[b][f][j] = (x @ W)^T (bf16) + fused colsum S ----------------
// (byte-identical since round 3)
__global__ __launch_bounds__(256) void k_gemm1(const float* __restrict__ x,
                                               const float* __restrict__ W,
                                               u16* __restrict__ Wht,
                                               float* __restrict__ S) {
    __shared__ __align__(16) u16 Wt[128][136];
    const int t = threadIdx.x;
    {
        int k = t >> 1;
        int f0 = (t & 1) * 64;
        const float4* wp = reinterpret_cast<const float4*>(W + k * 128 + f0);
#pragma unroll
        for (int q = 0; q < 16; ++q) {
            float4 v = wp[q];
            int f = f0 + q * 4;
            Wt[f + 0][k] = f2bf(v.x);
            Wt[f + 1][k] = f2bf(v.y);
            Wt[f + 2][k] = f2bf(v.z);
            Wt[f + 3][k] = f2bf(v.w);
        }
    }
    __syncthreads();

    const int w = t >> 6, l = t & 63;
    const int lr = l & 15, lg = l >> 4;
    const int fh = (w & 1) * 64;
    const int jh = (w >> 1) * 64;
    const int j0 = blockIdx.x * 128;

    f32x4 acc[4][4];
#pragma unroll
    for (int m = 0; m < 4; ++m)
#pragma unroll
        for (int n = 0; n < 4; ++n) acc[m][n] = (f32x4){0.f, 0.f, 0.f, 0.f};

#pragma unroll
    for (int ks = 0; ks < 4; ++ks) {
        bf16x8 a[4], bb[4];
#pragma unroll
        for (int m = 0; m < 4; ++m)
            a[m] = *reinterpret_cast<const bf16x8*>(&Wt[fh + m * 16 + lr][ks * 32 + lg * 8]);
#pragma unroll
        for (int n = 0; n < 4; ++n) {
            int j = j0 + jh + n * 16 + lr;
            const float* xp = x + (size_t)j * 128 + ks * 32 + lg * 8;
            float4 v0 = *reinterpret_cast<const float4*>(xp);
            float4 v1 = *reinterpret_cast<const float4*>(xp + 4);
            bf16x8 bv;
            bv[0] = (short)f2bf(v0.x); bv[1] = (short)f2bf(v0.y);
            bv[2] = (short)f2bf(v0.z); bv[3] = (short)f2bf(v0.w);
            bv[4] = (short)f2bf(v1.x); bv[5] = (short)f2bf(v1.y);
            bv[6] = (short)f2bf(v1.z); bv[7] = (short)f2bf(v1.w);
            bb[n] = bv;
        }
#pragma unroll
        for (int m = 0; m < 4; ++m)
#pragma unroll
            for (int n = 0; n < 4; ++n)
                acc[m][n] = __builtin_amdgcn_mfma_f32_16x16x32_bf16(a[m], bb[n], acc[m][n], 0, 0, 0);
    }

    const int bb_ = blockIdx.x >> 5;
    const int jj = (blockIdx.x & 31) * 128;
    u16* base = Wht + ((size_t)bb_ << 19);
    float* Sb = S + bb_ * 128;
#pragma unroll
    for (int m = 0; m < 4; ++m) {
        int f = fh + m * 16 + lg * 4;
#pragma unroll
        for (int n = 0; n < 4; ++n) {
            int j = jj + jh + n * 16 + lr;
#pragma unroll
            for (int r = 0; r < 4; ++r)
                base[(size_t)(f + r) * 4096 + j] = f2bf(acc[m][n][r]);
        }
#pragma unroll
        for (int r = 0; r < 4; ++r) {
            float sj = 0.f;
#pragma unroll
            for (int n = 0; n < 4; ++n) sj += acc[m][n][r];
            sj += __shfl_xor(sj, 1);
            sj += __shfl_xor(sj, 2);
            sj += __shfl_xor(sj, 4);
            sj += __shfl_xor(sj, 8);
            if (lr == 0) atomicAdd(&Sb[f + r], sj);
        }
    }
}

// convert 8 adj ints -> bf16x8 {0,1}, accumulating the nonzero count
__device__ inline bf16x8 conv8(int4 a, int4 b, int& c) {
    c += (a.x > 0) + (a.y > 0) + (a.z > 0) + (a.w > 0)
       + (b.x > 0) + (b.y > 0) + (b.z > 0) + (b.w > 0);
    u32 u0 = ((a.x > 0) ? 0x3F80u : 0u) | (((a.y > 0) ? 0x3F80u : 0u) << 16);
    u32 u1 = ((a.z > 0) ? 0x3F80u : 0u) | (((a.w > 0) ? 0x3F80u : 0u) << 16);
    u32 u2 = ((b.x > 0) ? 0x3F80u : 0u) | (((b.y > 0) ? 0x3F80u : 0u) << 16);
    u32 u3 = ((b.z > 0) ? 0x3F80u : 0u) | (((b.w > 0) ? 0x3F80u : 0u) << 16);
    uint4 q = make_uint4(u0, u1, u2, u3);
    return __builtin_bit_cast(bf16x8, q);
}

// ---------------- Kernel 2: partial[ksp][b][i][f] = sum_{j in half: adj>0} Wh[b][j][f] ----------------
// BARRIER-FREE, LDS-FREE: each wave owns 16 adj rows (ir=w) and all 8 f-frags.
// A-fragments load global->reg directly in MFMA layout (each adj byte read once);
// depth-2 register pipeline on A; B (L1/L2-resident panel) loaded just-in-time.
// 8 fully independent waves/CU.
__global__ __launch_bounds__(256, 2) void k_gemm2(const int* __restrict__ adj,
                                                  const u16* __restrict__ Wht,
                                                  float* __restrict__ part,   // [2][4][4096][128]
                                                  int* __restrict__ cnt) {    // [4*4096]
    const int t = threadIdx.x;
    const int raw = blockIdx.x;
    const int swz = (raw & 7) * 64 + (raw >> 3);  // XCD-bijective: 1 (b,ksp) panel per XCD
    const int b   = swz >> 7;
    const int ksp = (swz >> 6) & 1;
    const int i0  = (swz & 63) * 64;
    const int koff = ksp * 2048;

    const int w = t >> 6, l = t & 63;
    const int lr = l & 15, lg = l >> 4;
    const int arow = i0 + w * 16 + lr;   // the adj row this lane serves (distinct per wave)

    // A stream pointer: lane (lr,lg) reads row arow, k = kt*64 + ks*32 + lg*8 .. +7
    const int* apn = adj + ((size_t)b << 24) + (size_t)arow * 4096 + koff + lg * 8;
    const u16* whb = Wht + ((size_t)b << 19) + koff;

    // B fragment pointers: f-row n*16+lr, k-offset lg*8 (bumped +64 elems per step)
    const u16* bq[8];
#pragma unroll
    for (int n = 0; n < 8; ++n)
        bq[n] = whb + (size_t)(n * 16 + lr) * 4096 + lg * 8;

    int4 av[2][4];   // A reg double-buffer; parity-static indexing only
    int cntv = 0;
    f32x4 acc[8];
#pragma unroll
    for (int n = 0; n < 8; ++n) acc[n] = (f32x4){0.f, 0.f, 0.f, 0.f};

#define ISSUE_A(P)                                                   \
    {                                                                \
        const int4* _p = reinterpret_cast<const int4*>(apn);         \
        av[P][0] = _p[0]; av[P][1] = _p[1];   /* ks=0: +0,+16 B */   \
        av[P][2] = _p[8]; av[P][3] = _p[9];   /* ks=1: +128,+144 B */\
        apn += 64;                                                   \
    }

#define STEP(P, DO_ISSUE)                                                         \
    {                                                                             \
        bf16x8 a0 = conv8(av[P][0], av[P][1], cntv);                              \
        bf16x8 a1 = conv8(av[P][2], av[P][3], cntv);                              \
        if (DO_ISSUE) ISSUE_A(P);                                                 \
        bf16x8 b0[8], b1[8];                                                      \
        _Pragma("unroll")                                                         \
        for (int n = 0; n < 8; ++n) b0[n] = *reinterpret_cast<const bf16x8*>(bq[n]);      \
        _Pragma("unroll")                                                         \
        for (int n = 0; n < 8; ++n) b1[n] = *reinterpret_cast<const bf16x8*>(bq[n] + 32); \
        _Pragma("unroll")                                                         \
        for (int n = 0; n < 8; ++n)                                               \
            acc[n] = __builtin_amdgcn_mfma_f32_16x16x32_bf16(a0, b0[n], acc[n], 0, 0, 0); \
        _Pragma("unroll")                                                         \
        for (int n = 0; n < 8; ++n)                                               \
            acc[n] = __builtin_amdgcn_mfma_f32_16x16x32_bf16(a1, b1[n], acc[n], 0, 0, 0); \
        _Pragma("unroll")                                                         \
        for (int n = 0; n < 8; ++n) bq[n] += 64;                                  \
    }

    // prologue: tiles 0,1 in flight
    ISSUE_A(0);
    ISSUE_A(1);

    // 32 K-steps; each STEP consumes one tile and issues tile+2 (depth-2 pipeline)
    for (int kp = 0; kp < 15; ++kp) {
        STEP(0, 1);
        STEP(1, 1);
    }
    STEP(0, 0);   // tile 30
    STEP(1, 0);   // tile 31

#undef ISSUE_A
#undef STEP

    // per-row nonzero count for this K-half: lanes {lr, lr+16, lr+32, lr+48} hold
    // disjoint k-shares of row arow -> xor-reduce over the lg axis
    int c = cntv + __shfl_xor(cntv, 16);
    c += __shfl_xor(c, 32);
    if (lg == 0) atomicAdd(&cnt[b * 4096 + i0 + w * 16 + lr], c);

    // store partial sums: C layout col(f)=n*16+lr, row(i)=w*16+lg*4+r
    float* pb = part + ((size_t)ksp << 21) + ((size_t)b * 4096 + i0) * 128;
#pragma unroll
    for (int n = 0; n < 8; ++n) {
        int f = n * 16 + lr;
#pragma unroll
        for (int r = 0; r < 4; ++r) {
            int il = w * 16 + lg * 4 + r;
            pb[(size_t)il * 128 + f] = acc[n][r];
        }
    }
}

// ---------------- Kernel 3: out = (part0+part1)/cnt, empty-row fallback ----------------
__global__ __launch_bounds__(256) void k_fin(const float* __restrict__ part,
                                             const int* __restrict__ cnt,
                                             const float* __restrict__ S,
                                             float* __restrict__ out) {
    int e = blockIdx.x * 256 + threadIdx.x;  // 2M elements
    int f = e & 127;
    int row = e >> 7;      // b*4096 + i
    int b = row >> 12;
    int c = cnt[row];
    float p = part[e] + part[e + (1 << 21)];
    float v;
    if (c > 0) v = p / (float)c;
    else       v = S[b * 128 + f] * (1.0f / 4096.0f);  // uniform softmax over all-masked row
    out[e] = v;
}

extern "C" void kernel_launch(void* const* d_in, const int* in_sizes, int n_in,
                              void* d_out, int out_size, void* d_ws, size_t ws_size,
                              hipStream_t stream) {
    const float* x = (const float*)d_in[0];
    const int* adj = (const int*)d_in[1];
    const float* W = (const float*)d_in[2];
    // d_in[3] (a) is mathematically dead: softmax of a j-constant over the adj
    // support is uniform, so attention = adj / rowsum(adj).
    float* out = (float*)d_out;

    char* wsb = (char*)d_ws;
    float* S    = (float*)(wsb);                   // 512 f32 (2 KB)
    int*   cnt  = (int*)(wsb + 4096);              // 16384 i32 (64 KB)
    float* part = (float*)(wsb + (1u << 20));      // 2 x 8 MB f32 partials
    u16*   Wht  = (u16*)(wsb + (40u << 20));       // 4 MB bf16

    hipMemsetAsync(wsb, 0, 4096 + 65536, stream);  // zero S + cnt
    k_gemm1<<<128, 256, 0, stream>>>(x, W, Wht, S);
    k_gemm2<<<512, 256, 0, stream>>>(adj, Wht, part, cnt);
    k_fin<<<8192, 256, 0, stream>>>(part, cnt, S, out);
}